// Round 5
// baseline (1431.770 us; speedup 1.0000x reference)
//
#include <hip/hip_runtime.h>
#include <hip/hip_bf16.h>
#include <hip/hip_fp16.h>

typedef _Float16 f16;
typedef _Float16 f16x8 __attribute__((ext_vector_type(8)));
typedef float f32x4 __attribute__((ext_vector_type(4)));

#define SP 16384           // 128*128 spatial per batch
#define HALF_TILES 2048    // tiles per half (2 batches * 1024)
#define XF_BYTES ((size_t)HALF_TILES * 40960)

// xf tile layout (40 KB per tile, fragment-ready):
//   byte = t*8192 + k0*1024 + c*64 + g4*16  holds x[t, d=k0*32+g4*8+e, s=tile*16+c]

__global__ void prep_weights(const float* __restrict__ Wq,
                             const float* __restrict__ Wkv,
                             const float* __restrict__ Wp,
                             f16* __restrict__ wqT,
                             f16* __restrict__ wkvT,
                             f16* __restrict__ wpT) {
  const int f = threadIdx.x;
  const int k = blockIdx.x;
  wkvT[f * 256 + k] = (f16)Wkv[k * 512 + f];
  if (f < 256) {
    wqT[f * 256 + k] = (f16)Wq[k * 256 + f];
    wpT[f * 256 + k] = (f16)Wp[k * 256 + f];
  }
}

// Kernel A: transpose/cast x -> xf (fragment layout). Per block: (b_local, t,
// k0, sg): reads 32 rows x 1KB contiguous, writes 16 tiles x 1KB contiguous.
__global__ __launch_bounds__(256) void xpose(const float* __restrict__ x,
                                             f16* __restrict__ xf, int h) {
  __shared__ float ls[32 * 258];  // pad 258: read banks 2-way max
  const int blk = blockIdx.x;
  const int sg = blk & 63;          // s-chunk of 256
  const int k0 = (blk >> 6) & 7;    // d-chunk of 32
  const int t  = (blk >> 9) % 5;
  const int bl = blk / 2560;        // local batch 0..1
  const int tid = threadIdx.x;

  const float* xA = x + ((size_t)(((2 * h + bl) * 5 + t) * 256 + k0 * 32)) * SP
                      + sg * 256;
#pragma unroll
  for (int j = 0; j < 8; ++j) {
    const int qq = j * 256 + tid;
    const int dl = qq >> 6, s4 = qq & 63;
    const f32x4 v = *(const f32x4*)(xA + (size_t)dl * SP + s4 * 4);
    *(f32x4*)&ls[dl * 258 + s4 * 4] = v;
  }
  __syncthreads();

  const int tile_base = bl * 1024 + sg * 16;  // tile index within half
#pragma unroll
  for (int pp = 0; pp < 4; ++pp) {
    const int piece = pp * 256 + tid;   // 1024 pieces of 16B
    const int tt = piece >> 6;
    const int c  = (piece >> 2) & 15;
    const int g4 = piece & 3;
    f16x8 pk;
#pragma unroll
    for (int e = 0; e < 8; ++e)
      pk[e] = (f16)ls[(g4 * 8 + e) * 258 + tt * 16 + c];
    f16* dst = xf + (size_t)(tile_base + tt) * 20480 + t * 4096 + k0 * 512
                  + c * 32 + g4 * 8;
    *(f16x8*)dst = pk;
  }
}

// Kernel B: fused qkv GEMM + attention + projection. One tile per block.
__global__ __launch_bounds__(512, 6) void fused_attn(
    const f16* __restrict__ xf,
    const float* __restrict__ bq,
    const float* __restrict__ bkv,
    const float* __restrict__ bp,
    const float* __restrict__ pos_bias,
    const f16* __restrict__ wqT,
    const f16* __restrict__ wkvT,
    const f16* __restrict__ wpT,
    float* __restrict__ out, int h) {
  __shared__ f16 fb[5 * 16 * 256];  // 40 KB fragment tile
  __shared__ f16 as_[16 * 256];     // 8 KB attn-out

  const int tid = threadIdx.x;
  const int lane = tid & 63;
  const int w = tid >> 6;    // wave 0..7 -> heads 2w, 2w+1
  const int c = lane & 15;   // spatial index s within tile
  const int g4 = lane >> 4;  // k-group
  const int hA = 2 * w;

  const int g = h * HALF_TILES + blockIdx.x;
  const int b = g >> 10, s0 = (g & 1023) << 4;

  // ---- stage tile: 10 x global_load_lds(16B) per wave, sequential 40 KB ----
  {
    const char* src = (const char*)xf + (size_t)blockIdx.x * 40960 + w * 5120
                      + lane * 16;
    char* dst = (char*)fb + w * 5120 + lane * 16;
#pragma unroll
    for (int n = 0; n < 10; ++n) {
      __builtin_amdgcn_global_load_lds(
          (const void __attribute__((address_space(1)))*)(src + n * 512),
          (void __attribute__((address_space(3)))*)(dst + n * 512), 16, 0, 0);
    }
  }

  // ---- hoisted per-lane constants ----
  float pb[2][5], bpv[2], bqr[2][4], bkr[2][4], bvr[2][4];
#pragma unroll
  for (int j = 0; j < 2; ++j) {
    const int hj = hA + j;
    bpv[j] = bp[hj * 16 + c];
#pragma unroll
    for (int t = 0; t < 5; ++t) pb[j][t] = pos_bias[hj * 5 + t];
#pragma unroll
    for (int rr = 0; rr < 4; ++rr) {
      bqr[j][rr] = bq[hj * 16 + 4 * g4 + rr];
      bkr[j][rr] = bkv[hj * 16 + 4 * g4 + rr];
      bvr[j][rr] = bkv[256 + hj * 16 + 4 * g4 + rr];
    }
  }
  const f16* wqp0 = wqT + (hA * 16 + c) * 256;
  const f16* wqp1 = wqT + ((hA + 1) * 16 + c) * 256;
  const f16* wkp0 = wkvT + (hA * 16 + c) * 256;
  const f16* wkp1 = wkvT + ((hA + 1) * 16 + c) * 256;
  const f16* wvp0 = wkvT + (256 + hA * 16 + c) * 256;
  const f16* wvp1 = wkvT + (256 + (hA + 1) * 16 + c) * 256;
  const f16* wpp0 = wpT + (hA * 16 + c) * 256;
  const f16* wpp1 = wpT + ((hA + 1) * 16 + c) * 256;

  __syncthreads();  // drains gll (vmcnt 0): fb ready

  // ---- q/k/v GEMM, swapped operands: C[m=dk][n=s] ----
  f32x4 qacc[2] = {};
  f32x4 kacc[2][5] = {};
  f32x4 vacc[2][5] = {};
  const char* fbp = (const char*)fb;
#pragma unroll 1
  for (int k0 = 0; k0 < 8; ++k0) {
    const int base = (k0 << 10) + (c << 6) + (g4 << 4);
    f16x8 xfr[5];
#pragma unroll
    for (int t = 0; t < 5; ++t) xfr[t] = *(const f16x8*)(fbp + (t << 13) + base);
    const int kk = (k0 << 5) + (g4 << 3);
    const f16x8 fq0 = *(const f16x8*)(wqp0 + kk);
    const f16x8 fq1 = *(const f16x8*)(wqp1 + kk);
    const f16x8 fk0 = *(const f16x8*)(wkp0 + kk);
    const f16x8 fk1 = *(const f16x8*)(wkp1 + kk);
    const f16x8 fv0 = *(const f16x8*)(wvp0 + kk);
    const f16x8 fv1 = *(const f16x8*)(wvp1 + kk);

    qacc[0] = __builtin_amdgcn_mfma_f32_16x16x32_f16(fq0, xfr[0], qacc[0], 0, 0, 0);
    qacc[1] = __builtin_amdgcn_mfma_f32_16x16x32_f16(fq1, xfr[0], qacc[1], 0, 0, 0);
#pragma unroll
    for (int t = 0; t < 5; ++t) {
      kacc[0][t] = __builtin_amdgcn_mfma_f32_16x16x32_f16(fk0, xfr[t], kacc[0][t], 0, 0, 0);
      kacc[1][t] = __builtin_amdgcn_mfma_f32_16x16x32_f16(fk1, xfr[t], kacc[1][t], 0, 0, 0);
      vacc[0][t] = __builtin_amdgcn_mfma_f32_16x16x32_f16(fv0, xfr[t], vacc[0][t], 0, 0, 0);
      vacc[1][t] = __builtin_amdgcn_mfma_f32_16x16x32_f16(fv1, xfr[t], vacc[1][t], 0, 0, 0);
    }
  }

  // ---- attention: lane holds q/k/v[dk=4g4+rr][s=c] ----
#pragma unroll
  for (int j = 0; j < 2; ++j) {
    float qv[4];
#pragma unroll
    for (int rr = 0; rr < 4; ++rr) qv[rr] = qacc[j][rr] + bqr[j][rr];
    float sc[5];
#pragma unroll
    for (int t = 0; t < 5; ++t) {
      float p = 0.f;
#pragma unroll
      for (int rr = 0; rr < 4; ++rr) p += qv[rr] * (kacc[j][t][rr] + bkr[j][rr]);
      p += __shfl_xor(p, 16);
      p += __shfl_xor(p, 32);
      sc[t] = p * 4.0f + pb[j][t];  // /temperature (=0.25) + pos_bias
    }
    float m = sc[0];
#pragma unroll
    for (int t = 1; t < 5; ++t) m = fmaxf(m, sc[t]);
    float l = 0.f;
#pragma unroll
    for (int t = 0; t < 5; ++t) { sc[t] = __expf(sc[t] - m); l += sc[t]; }
    const float inv = 1.0f / l;
    float oo[4];
#pragma unroll
    for (int rr = 0; rr < 4; ++rr) {
      float o = 0.f;
#pragma unroll
      for (int t = 0; t < 5; ++t) o += sc[t] * (vacc[j][t][rr] + bvr[j][rr]);
      oo[rr] = o * inv;
    }
    const int hj = hA + j;
#pragma unroll
    for (int pr = 0; pr < 2; ++pr) {
      const int feat0 = hj * 16 + 4 * g4 + 2 * pr;
      const int byte = ((feat0 >> 5) << 10) + (c << 6) +
                       ((((feat0 >> 3) & 3) ^ (c & 3)) << 4) + ((feat0 & 7) << 1);
      union { f16 hh[2]; unsigned u; } pk;
      pk.hh[0] = (f16)oo[2 * pr];
      pk.hh[1] = (f16)oo[2 * pr + 1];
      *(unsigned*)((char*)as_ + byte) = pk.u;
    }
  }
  __syncthreads();  // as_ visible

  // ---- projection: attn_out[16s x 256] @ Wp -> C[m=s][n=feat_out] ----
  f32x4 facc[2] = {};
#pragma unroll 1
  for (int k0 = 0; k0 < 8; ++k0) {
    const f16x8 af = *(const f16x8*)((const char*)as_ + (k0 << 10) + (c << 6) +
                                     ((g4 ^ (c & 3)) << 4));
    const int kk = (k0 << 5) + (g4 << 3);
    const f16x8 f0 = *(const f16x8*)(wpp0 + kk);
    const f16x8 f1 = *(const f16x8*)(wpp1 + kk);
    facc[0] = __builtin_amdgcn_mfma_f32_16x16x32_f16(af, f0, facc[0], 0, 0, 0);
    facc[1] = __builtin_amdgcn_mfma_f32_16x16x32_f16(af, f1, facc[1], 0, 0, 0);
  }

  // ---- store: out[b, dg, s0 + 4*g4 + rr] ----
#pragma unroll
  for (int j = 0; j < 2; ++j) {
    const int dg = (hA + j) * 16 + c;
    f32x4 vs = facc[j];
#pragma unroll
    for (int rr = 0; rr < 4; ++rr) vs[rr] += bpv[j];
    float* dst = out + ((size_t)b * 256 + dg) * SP + s0 + (g4 << 2);
    *(f32x4*)dst = vs;
  }
}

extern "C" void kernel_launch(void* const* d_in, const int* in_sizes, int n_in,
                              void* d_out, int out_size, void* d_ws, size_t ws_size,
                              hipStream_t stream) {
  const float* x   = (const float*)d_in[0];
  const float* Wq  = (const float*)d_in[1];
  const float* bq  = (const float*)d_in[2];
  const float* Wkv = (const float*)d_in[3];
  const float* bkv = (const float*)d_in[4];
  const float* Wp  = (const float*)d_in[5];
  const float* bp  = (const float*)d_in[6];
  const float* pos = (const float*)d_in[7];

  f16* xf   = (f16*)d_ws;                              // 84 MB (reused per half)
  f16* wqT  = (f16*)((char*)d_ws + XF_BYTES);          // 256*256
  f16* wkvT = wqT + 256 * 256;                         // 512*256
  f16* wpT  = wkvT + 512 * 256;                        // 256*256

  prep_weights<<<256, 512, 0, stream>>>(Wq, Wkv, Wp, wqT, wkvT, wpT);
  for (int h = 0; h < 2; ++h) {
    xpose<<<5120, 256, 0, stream>>>(x, xf, h);
    fused_attn<<<HALF_TILES, 512, 0, stream>>>(xf, bq, bkv, bp, pos,
                                               wqT, wkvT, wpT,
                                               (float*)d_out, h);
  }
}

// Round 6
// 447.636 us; speedup vs baseline: 3.1985x; 3.1985x over previous
//
#include <hip/hip_runtime.h>
#include <hip/hip_bf16.h>
#include <hip/hip_fp16.h>

typedef _Float16 f16;
typedef _Float16 f16x8 __attribute__((ext_vector_type(8)));
typedef float f32x4 __attribute__((ext_vector_type(4)));

#define SP 16384           // 128*128 spatial per batch
#define HALF_TILES 2048    // tiles per half (2 batches * 1024)
#define XF_BYTES ((size_t)HALF_TILES * 40960)

// xf tile layout (40 KB per tile, fragment-ready):
//   byte = t*8192 + k0*1024 + c*64 + g4*16  holds x[t, d=k0*32+g4*8+e, s=tile*16+c]

__global__ void prep_weights(const float* __restrict__ Wq,
                             const float* __restrict__ Wkv,
                             const float* __restrict__ Wp,
                             f16* __restrict__ wqT,
                             f16* __restrict__ wkvT,
                             f16* __restrict__ wpT) {
  const int f = threadIdx.x;
  const int k = blockIdx.x;
  wkvT[f * 256 + k] = (f16)Wkv[k * 512 + f];
  if (f < 256) {
    wqT[f * 256 + k] = (f16)Wq[k * 256 + f];
    wpT[f * 256 + k] = (f16)Wp[k * 256 + f];
  }
}

// Kernel A: transpose/cast x -> xf (fragment layout). Per block: (b_local, t,
// k0, sg): reads 32 rows x 1KB contiguous, writes 16 tiles x 1KB contiguous.
__global__ __launch_bounds__(256) void xpose(const float* __restrict__ x,
                                             f16* __restrict__ xf, int h) {
  __shared__ float ls[32 * 258];  // pad 258: read banks 2-way max
  const int blk = blockIdx.x;
  const int sg = blk & 63;          // s-chunk of 256
  const int k0 = (blk >> 6) & 7;    // d-chunk of 32
  const int t  = (blk >> 9) % 5;
  const int bl = blk / 2560;        // local batch 0..1
  const int tid = threadIdx.x;

  const float* xA = x + ((size_t)(((2 * h + bl) * 5 + t) * 256 + k0 * 32)) * SP
                      + sg * 256;
#pragma unroll
  for (int j = 0; j < 8; ++j) {
    const int qq = j * 256 + tid;
    const int dl = qq >> 6, s4 = qq & 63;
    const f32x4 v = *(const f32x4*)(xA + (size_t)dl * SP + s4 * 4);
    *(f32x4*)&ls[dl * 258 + s4 * 4] = v;
  }
  __syncthreads();

  const int tile_base = bl * 1024 + sg * 16;  // tile index within half
#pragma unroll
  for (int pp = 0; pp < 4; ++pp) {
    const int piece = pp * 256 + tid;   // 1024 pieces of 16B
    const int tt = piece >> 6;
    const int c  = (piece >> 2) & 15;
    const int g4 = piece & 3;
    f16x8 pk;
#pragma unroll
    for (int e = 0; e < 8; ++e)
      pk[e] = (f16)ls[(g4 * 8 + e) * 258 + tt * 16 + c];
    f16* dst = xf + (size_t)(tile_base + tt) * 20480 + t * 4096 + k0 * 512
                  + c * 32 + g4 * 8;
    *(f16x8*)dst = pk;
  }
}

// Kernel B: fused qkv GEMM + attention + projection. One tile per block.
// launch_bounds(512,4): 4 waves/EU -> VGPR cap 128 (kernel needs ~116; 6
// waves/EU capped at 85 and spilled 1.8 GB of scratch in R5).
__global__ __launch_bounds__(512, 4) void fused_attn(
    const f16* __restrict__ xf,
    const float* __restrict__ bq,
    const float* __restrict__ bkv,
    const float* __restrict__ bp,
    const float* __restrict__ pos_bias,
    const f16* __restrict__ wqT,
    const f16* __restrict__ wkvT,
    const f16* __restrict__ wpT,
    float* __restrict__ out, int h) {
  __shared__ f16 fb[5 * 16 * 256];  // 40 KB fragment tile
  __shared__ f16 as_[16 * 256];     // 8 KB attn-out

  const int tid = threadIdx.x;
  const int lane = tid & 63;
  const int w = tid >> 6;    // wave 0..7 -> heads 2w, 2w+1
  const int c = lane & 15;   // spatial index s within tile
  const int g4 = lane >> 4;  // k-group
  const int hA = 2 * w;

  const int g = h * HALF_TILES + blockIdx.x;
  const int b = g >> 10, s0 = (g & 1023) << 4;

  // ---- stage tile: 10 x global_load_lds(16B) per wave, sequential 40 KB ----
  {
    const char* src = (const char*)xf + (size_t)blockIdx.x * 40960 + w * 5120
                      + lane * 16;
    char* dst = (char*)fb + w * 5120 + lane * 16;
#pragma unroll
    for (int n = 0; n < 10; ++n) {
      __builtin_amdgcn_global_load_lds(
          (const void __attribute__((address_space(1)))*)(src + n * 512),
          (void __attribute__((address_space(3)))*)(dst + n * 512), 16, 0, 0);
    }
  }

  // ---- hoisted per-lane constants ----
  float pb[2][5], bpv[2], bqr[2][4], bkr[2][4], bvr[2][4];
#pragma unroll
  for (int j = 0; j < 2; ++j) {
    const int hj = hA + j;
    bpv[j] = bp[hj * 16 + c];
#pragma unroll
    for (int t = 0; t < 5; ++t) pb[j][t] = pos_bias[hj * 5 + t];
#pragma unroll
    for (int rr = 0; rr < 4; ++rr) {
      bqr[j][rr] = bq[hj * 16 + 4 * g4 + rr];
      bkr[j][rr] = bkv[hj * 16 + 4 * g4 + rr];
      bvr[j][rr] = bkv[256 + hj * 16 + 4 * g4 + rr];
    }
  }
  const f16* wqp0 = wqT + (hA * 16 + c) * 256;
  const f16* wqp1 = wqT + ((hA + 1) * 16 + c) * 256;
  const f16* wkp0 = wkvT + (hA * 16 + c) * 256;
  const f16* wkp1 = wkvT + ((hA + 1) * 16 + c) * 256;
  const f16* wvp0 = wkvT + (256 + hA * 16 + c) * 256;
  const f16* wvp1 = wkvT + (256 + (hA + 1) * 16 + c) * 256;
  const f16* wpp0 = wpT + (hA * 16 + c) * 256;
  const f16* wpp1 = wpT + ((hA + 1) * 16 + c) * 256;

  __syncthreads();  // drains gll (vmcnt 0): fb ready

  // ---- q/k/v GEMM, swapped operands: C[m=dk][n=s] ----
  f32x4 qacc[2] = {};
  f32x4 kacc[2][5] = {};
  f32x4 vacc[2][5] = {};
  const char* fbp = (const char*)fb;
#pragma unroll 1
  for (int k0 = 0; k0 < 8; ++k0) {
    const int base = (k0 << 10) + (c << 6) + (g4 << 4);
    f16x8 xfr[5];
#pragma unroll
    for (int t = 0; t < 5; ++t) xfr[t] = *(const f16x8*)(fbp + (t << 13) + base);
    const int kk = (k0 << 5) + (g4 << 3);
    const f16x8 fq0 = *(const f16x8*)(wqp0 + kk);
    const f16x8 fq1 = *(const f16x8*)(wqp1 + kk);
    const f16x8 fk0 = *(const f16x8*)(wkp0 + kk);
    const f16x8 fk1 = *(const f16x8*)(wkp1 + kk);
    const f16x8 fv0 = *(const f16x8*)(wvp0 + kk);
    const f16x8 fv1 = *(const f16x8*)(wvp1 + kk);

    qacc[0] = __builtin_amdgcn_mfma_f32_16x16x32_f16(fq0, xfr[0], qacc[0], 0, 0, 0);
    qacc[1] = __builtin_amdgcn_mfma_f32_16x16x32_f16(fq1, xfr[0], qacc[1], 0, 0, 0);
#pragma unroll
    for (int t = 0; t < 5; ++t) {
      kacc[0][t] = __builtin_amdgcn_mfma_f32_16x16x32_f16(fk0, xfr[t], kacc[0][t], 0, 0, 0);
      kacc[1][t] = __builtin_amdgcn_mfma_f32_16x16x32_f16(fk1, xfr[t], kacc[1][t], 0, 0, 0);
      vacc[0][t] = __builtin_amdgcn_mfma_f32_16x16x32_f16(fv0, xfr[t], vacc[0][t], 0, 0, 0);
      vacc[1][t] = __builtin_amdgcn_mfma_f32_16x16x32_f16(fv1, xfr[t], vacc[1][t], 0, 0, 0);
    }
  }

  // ---- attention: lane holds q/k/v[dk=4g4+rr][s=c] ----
#pragma unroll
  for (int j = 0; j < 2; ++j) {
    float qv[4];
#pragma unroll
    for (int rr = 0; rr < 4; ++rr) qv[rr] = qacc[j][rr] + bqr[j][rr];
    float sc[5];
#pragma unroll
    for (int t = 0; t < 5; ++t) {
      float p = 0.f;
#pragma unroll
      for (int rr = 0; rr < 4; ++rr) p += qv[rr] * (kacc[j][t][rr] + bkr[j][rr]);
      p += __shfl_xor(p, 16);
      p += __shfl_xor(p, 32);
      sc[t] = p * 4.0f + pb[j][t];  // /temperature (=0.25) + pos_bias
    }
    float m = sc[0];
#pragma unroll
    for (int t = 1; t < 5; ++t) m = fmaxf(m, sc[t]);
    float l = 0.f;
#pragma unroll
    for (int t = 0; t < 5; ++t) { sc[t] = __expf(sc[t] - m); l += sc[t]; }
    const float inv = 1.0f / l;
    float oo[4];
#pragma unroll
    for (int rr = 0; rr < 4; ++rr) {
      float o = 0.f;
#pragma unroll
      for (int t = 0; t < 5; ++t) o += sc[t] * (vacc[j][t][rr] + bvr[j][rr]);
      oo[rr] = o * inv;
    }
    const int hj = hA + j;
#pragma unroll
    for (int pr = 0; pr < 2; ++pr) {
      const int feat0 = hj * 16 + 4 * g4 + 2 * pr;
      const int byte = ((feat0 >> 5) << 10) + (c << 6) +
                       ((((feat0 >> 3) & 3) ^ (c & 3)) << 4) + ((feat0 & 7) << 1);
      union { f16 hh[2]; unsigned u; } pk;
      pk.hh[0] = (f16)oo[2 * pr];
      pk.hh[1] = (f16)oo[2 * pr + 1];
      *(unsigned*)((char*)as_ + byte) = pk.u;
    }
  }
  __syncthreads();  // as_ visible

  // ---- projection: attn_out[16s x 256] @ Wp -> C[m=s][n=feat_out] ----
  f32x4 facc[2] = {};
#pragma unroll 1
  for (int k0 = 0; k0 < 8; ++k0) {
    const f16x8 af = *(const f16x8*)((const char*)as_ + (k0 << 10) + (c << 6) +
                                     ((g4 ^ (c & 3)) << 4));
    const int kk = (k0 << 5) + (g4 << 3);
    const f16x8 f0 = *(const f16x8*)(wpp0 + kk);
    const f16x8 f1 = *(const f16x8*)(wpp1 + kk);
    facc[0] = __builtin_amdgcn_mfma_f32_16x16x32_f16(af, f0, facc[0], 0, 0, 0);
    facc[1] = __builtin_amdgcn_mfma_f32_16x16x32_f16(af, f1, facc[1], 0, 0, 0);
  }

  // ---- store: out[b, dg, s0 + 4*g4 + rr] ----
#pragma unroll
  for (int j = 0; j < 2; ++j) {
    const int dg = (hA + j) * 16 + c;
    f32x4 vs = facc[j];
#pragma unroll
    for (int rr = 0; rr < 4; ++rr) vs[rr] += bpv[j];
    float* dst = out + ((size_t)b * 256 + dg) * SP + s0 + (g4 << 2);
    *(f32x4*)dst = vs;
  }
}

extern "C" void kernel_launch(void* const* d_in, const int* in_sizes, int n_in,
                              void* d_out, int out_size, void* d_ws, size_t ws_size,
                              hipStream_t stream) {
  const float* x   = (const float*)d_in[0];
  const float* Wq  = (const float*)d_in[1];
  const float* bq  = (const float*)d_in[2];
  const float* Wkv = (const float*)d_in[3];
  const float* bkv = (const float*)d_in[4];
  const float* Wp  = (const float*)d_in[5];
  const float* bp  = (const float*)d_in[6];
  const float* pos = (const float*)d_in[7];

  f16* xf   = (f16*)d_ws;                              // 84 MB (reused per half)
  f16* wqT  = (f16*)((char*)d_ws + XF_BYTES);          // 256*256
  f16* wkvT = wqT + 256 * 256;                         // 512*256
  f16* wpT  = wkvT + 512 * 256;                        // 256*256

  prep_weights<<<256, 512, 0, stream>>>(Wq, Wkv, Wp, wqT, wkvT, wpT);
  for (int h = 0; h < 2; ++h) {
    xpose<<<5120, 256, 0, stream>>>(x, xf, h);
    fused_attn<<<HALF_TILES, 512, 0, stream>>>(xf, bq, bkv, bp, pos,
                                               wqT, wkvT, wpT,
                                               (float*)d_out, h);
  }
}

// Round 7
// 280.678 us; speedup vs baseline: 5.1011x; 1.5948x over previous
//
#include <hip/hip_runtime.h>
#include <hip/hip_bf16.h>
#include <hip/hip_fp16.h>

typedef _Float16 f16;
typedef _Float16 f16x8 __attribute__((ext_vector_type(8)));
typedef float f32x4 __attribute__((ext_vector_type(4)));

#define SP 16384           // 128*128 spatial per batch
#define HALF_TILES 2048    // 16-spatial tiles per half (2 batches * 1024)
#define XF_BYTES ((size_t)HALF_TILES * 40960)

// xf tile layout (40 KB per 16-spatial tile, fragment-ready):
//   byte = t*8192 + k0*1024 + c*64 + g4*16  holds x[t, d=k0*32+g4*8+e, s=tile*16+c]

__global__ void prep_weights(const float* __restrict__ Wq,
                             const float* __restrict__ Wkv,
                             const float* __restrict__ Wp,
                             f16* __restrict__ wqT,
                             f16* __restrict__ wkvT,
                             f16* __restrict__ wpT) {
  const int f = threadIdx.x;
  const int k = blockIdx.x;
  wkvT[f * 256 + k] = (f16)Wkv[k * 512 + f];
  if (f < 256) {
    wqT[f * 256 + k] = (f16)Wq[k * 256 + f];
    wpT[f * 256 + k] = (f16)Wp[k * 256 + f];
  }
}

// Kernel A: transpose/cast x -> xf (fragment layout).
__global__ __launch_bounds__(256) void xpose(const float* __restrict__ x,
                                             f16* __restrict__ xf, int h) {
  __shared__ float ls[32 * 258];
  const int blk = blockIdx.x;
  const int sg = blk & 63;
  const int k0 = (blk >> 6) & 7;
  const int t  = (blk >> 9) % 5;
  const int bl = blk / 2560;
  const int tid = threadIdx.x;

  const float* xA = x + ((size_t)(((2 * h + bl) * 5 + t) * 256 + k0 * 32)) * SP
                      + sg * 256;
#pragma unroll
  for (int j = 0; j < 8; ++j) {
    const int qq = j * 256 + tid;
    const int dl = qq >> 6, s4 = qq & 63;
    const f32x4 v = *(const f32x4*)(xA + (size_t)dl * SP + s4 * 4);
    *(f32x4*)&ls[dl * 258 + s4 * 4] = v;
  }
  __syncthreads();

  const int tile_base = bl * 1024 + sg * 16;
#pragma unroll
  for (int pp = 0; pp < 4; ++pp) {
    const int piece = pp * 256 + tid;
    const int tt = piece >> 6;
    const int c  = (piece >> 2) & 15;
    const int g4 = piece & 3;
    f16x8 pk;
#pragma unroll
    for (int e = 0; e < 8; ++e)
      pk[e] = (f16)ls[(g4 * 8 + e) * 258 + tt * 16 + c];
    f16* dst = xf + (size_t)(tile_base + tt) * 20480 + t * 4096 + k0 * 512
                  + c * 32 + g4 * 8;
    *(f16x8*)dst = pk;
  }
}

// Kernel B: 2 tiles (32 spatial) per block; tile-loop inside each k-step so
// one weight-fragment load feeds 2x the MFMA work. launch_bounds(512,2):
// 256-reg unified cap (acc=176 + frags ~50 fits; NEVER request more than
// 2 waves/EU for this kernel -- 3 spill incidents say so).
__global__ __launch_bounds__(512, 2) void fused_attn(
    const f16* __restrict__ xf,
    const float* __restrict__ bq,
    const float* __restrict__ bkv,
    const float* __restrict__ bp,
    const float* __restrict__ pos_bias,
    const f16* __restrict__ wqT,
    const f16* __restrict__ wkvT,
    const f16* __restrict__ wpT,
    float* __restrict__ out, int h) {
  __shared__ f16 fb[2 * 5 * 16 * 256];  // 2 x 40 KB fragment tiles
  __shared__ f16 as_[2 * 16 * 256];     // 2 x 8 KB attn-out

  const int tid = threadIdx.x;
  const int lane = tid & 63;
  const int w = tid >> 6;    // wave 0..7 -> heads 2w, 2w+1
  const int c = lane & 15;
  const int g4 = lane >> 4;
  const int hA = 2 * w;

  const int g0 = h * HALF_TILES + blockIdx.x * 2;  // tiles g0, g0+1

  // ---- stage both tiles: 20 x global_load_lds(16B) per wave ----
#pragma unroll
  for (int u = 0; u < 2; ++u) {
    const char* src = (const char*)xf + ((size_t)blockIdx.x * 2 + u) * 40960
                      + w * 5120 + lane * 16;
    char* dst = (char*)fb + u * 40960 + w * 5120 + lane * 16;
#pragma unroll
    for (int n = 0; n < 10; ++n) {
      __builtin_amdgcn_global_load_lds(
          (const void __attribute__((address_space(1)))*)(src + n * 512),
          (void __attribute__((address_space(3)))*)(dst + n * 512), 16, 0, 0);
    }
  }

  // ---- hoisted per-lane constants ----
  float pb[2][5], bpv[2], bqr[2][4], bkr[2][4], bvr[2][4];
#pragma unroll
  for (int j = 0; j < 2; ++j) {
    const int hj = hA + j;
    bpv[j] = bp[hj * 16 + c];
#pragma unroll
    for (int t = 0; t < 5; ++t) pb[j][t] = pos_bias[hj * 5 + t];
#pragma unroll
    for (int rr = 0; rr < 4; ++rr) {
      bqr[j][rr] = bq[hj * 16 + 4 * g4 + rr];
      bkr[j][rr] = bkv[hj * 16 + 4 * g4 + rr];
      bvr[j][rr] = bkv[256 + hj * 16 + 4 * g4 + rr];
    }
  }
  const f16* wqp0 = wqT + (hA * 16 + c) * 256;
  const f16* wqp1 = wqT + ((hA + 1) * 16 + c) * 256;
  const f16* wkp0 = wkvT + (hA * 16 + c) * 256;
  const f16* wkp1 = wkvT + ((hA + 1) * 16 + c) * 256;
  const f16* wvp0 = wkvT + (256 + hA * 16 + c) * 256;
  const f16* wvp1 = wkvT + (256 + (hA + 1) * 16 + c) * 256;
  const f16* wpp0 = wpT + (hA * 16 + c) * 256;
  const f16* wpp1 = wpT + ((hA + 1) * 16 + c) * 256;

  __syncthreads();  // drains gll: fb ready

  // ---- q/k/v GEMM: one weight-frag set per k0 feeds both tiles ----
  f32x4 qacc[2][2] = {};      // [tile][head]
  f32x4 kacc[2][2][5] = {};
  f32x4 vacc[2][2][5] = {};
#pragma unroll 1
  for (int k0 = 0; k0 < 8; ++k0) {
    const int kk = (k0 << 5) + (g4 << 3);
    const f16x8 fq0 = *(const f16x8*)(wqp0 + kk);
    const f16x8 fq1 = *(const f16x8*)(wqp1 + kk);
    const f16x8 fk0 = *(const f16x8*)(wkp0 + kk);
    const f16x8 fk1 = *(const f16x8*)(wkp1 + kk);
    const f16x8 fv0 = *(const f16x8*)(wvp0 + kk);
    const f16x8 fv1 = *(const f16x8*)(wvp1 + kk);
    const int base = (k0 << 10) + (c << 6) + (g4 << 4);
#pragma unroll
    for (int u = 0; u < 2; ++u) {
      const char* fbp = (const char*)fb + u * 40960;
      f16x8 xfr[5];
#pragma unroll
      for (int t = 0; t < 5; ++t) xfr[t] = *(const f16x8*)(fbp + (t << 13) + base);

      qacc[u][0] = __builtin_amdgcn_mfma_f32_16x16x32_f16(fq0, xfr[0], qacc[u][0], 0, 0, 0);
      qacc[u][1] = __builtin_amdgcn_mfma_f32_16x16x32_f16(fq1, xfr[0], qacc[u][1], 0, 0, 0);
#pragma unroll
      for (int t = 0; t < 5; ++t) {
        kacc[u][0][t] = __builtin_amdgcn_mfma_f32_16x16x32_f16(fk0, xfr[t], kacc[u][0][t], 0, 0, 0);
        kacc[u][1][t] = __builtin_amdgcn_mfma_f32_16x16x32_f16(fk1, xfr[t], kacc[u][1][t], 0, 0, 0);
        vacc[u][0][t] = __builtin_amdgcn_mfma_f32_16x16x32_f16(fv0, xfr[t], vacc[u][0][t], 0, 0, 0);
        vacc[u][1][t] = __builtin_amdgcn_mfma_f32_16x16x32_f16(fv1, xfr[t], vacc[u][1][t], 0, 0, 0);
      }
    }
  }

  // ---- attention per tile (lane holds q/k/v[dk=4g4+rr][s=c]) ----
#pragma unroll
  for (int u = 0; u < 2; ++u) {
#pragma unroll
    for (int j = 0; j < 2; ++j) {
      float qv[4];
#pragma unroll
      for (int rr = 0; rr < 4; ++rr) qv[rr] = qacc[u][j][rr] + bqr[j][rr];
      float sc[5];
#pragma unroll
      for (int t = 0; t < 5; ++t) {
        float p = 0.f;
#pragma unroll
        for (int rr = 0; rr < 4; ++rr) p += qv[rr] * (kacc[u][j][t][rr] + bkr[j][rr]);
        p += __shfl_xor(p, 16);
        p += __shfl_xor(p, 32);
        sc[t] = p * 4.0f + pb[j][t];
      }
      float m = sc[0];
#pragma unroll
      for (int t = 1; t < 5; ++t) m = fmaxf(m, sc[t]);
      float l = 0.f;
#pragma unroll
      for (int t = 0; t < 5; ++t) { sc[t] = __expf(sc[t] - m); l += sc[t]; }
      const float inv = 1.0f / l;
      float oo[4];
#pragma unroll
      for (int rr = 0; rr < 4; ++rr) {
        float o = 0.f;
#pragma unroll
        for (int t = 0; t < 5; ++t) o += sc[t] * (vacc[u][j][t][rr] + bvr[j][rr]);
        oo[rr] = o * inv;
      }
      const int hj = hA + j;
#pragma unroll
      for (int pr = 0; pr < 2; ++pr) {
        const int feat0 = hj * 16 + 4 * g4 + 2 * pr;
        const int byte = ((feat0 >> 5) << 10) + (c << 6) +
                         ((((feat0 >> 3) & 3) ^ (c & 3)) << 4) + ((feat0 & 7) << 1);
        union { f16 hh[2]; unsigned uu; } pk;
        pk.hh[0] = (f16)oo[2 * pr];
        pk.hh[1] = (f16)oo[2 * pr + 1];
        *(unsigned*)((char*)as_ + u * 8192 + byte) = pk.uu;
      }
    }
  }
  __syncthreads();  // as_ visible

  // ---- projection: one wp-frag set per k0 feeds both tiles ----
  f32x4 facc[2][2] = {};
#pragma unroll 1
  for (int k0 = 0; k0 < 8; ++k0) {
    const int kk = (k0 << 5) + (g4 << 3);
    const f16x8 f0 = *(const f16x8*)(wpp0 + kk);
    const f16x8 f1 = *(const f16x8*)(wpp1 + kk);
    const int abyte = (k0 << 10) + (c << 6) + ((g4 ^ (c & 3)) << 4);
#pragma unroll
    for (int u = 0; u < 2; ++u) {
      const f16x8 af = *(const f16x8*)((const char*)as_ + u * 8192 + abyte);
      facc[u][0] = __builtin_amdgcn_mfma_f32_16x16x32_f16(af, f0, facc[u][0], 0, 0, 0);
      facc[u][1] = __builtin_amdgcn_mfma_f32_16x16x32_f16(af, f1, facc[u][1], 0, 0, 0);
    }
  }

  // ---- store ----
#pragma unroll
  for (int u = 0; u < 2; ++u) {
    const int g = g0 + u;
    const int b = g >> 10, s0 = (g & 1023) << 4;
#pragma unroll
    for (int j = 0; j < 2; ++j) {
      const int dg = (hA + j) * 16 + c;
      f32x4 vs = facc[u][j];
#pragma unroll
      for (int rr = 0; rr < 4; ++rr) vs[rr] += bpv[j];
      float* dst = out + ((size_t)b * 256 + dg) * SP + s0 + (g4 << 2);
      *(f32x4*)dst = vs;
    }
  }
}

extern "C" void kernel_launch(void* const* d_in, const int* in_sizes, int n_in,
                              void* d_out, int out_size, void* d_ws, size_t ws_size,
                              hipStream_t stream) {
  const float* x   = (const float*)d_in[0];
  const float* Wq  = (const float*)d_in[1];
  const float* bq  = (const float*)d_in[2];
  const float* Wkv = (const float*)d_in[3];
  const float* bkv = (const float*)d_in[4];
  const float* Wp  = (const float*)d_in[5];
  const float* bp  = (const float*)d_in[6];
  const float* pos = (const float*)d_in[7];

  f16* xf   = (f16*)d_ws;                              // 84 MB (reused per half)
  f16* wqT  = (f16*)((char*)d_ws + XF_BYTES);
  f16* wkvT = wqT + 256 * 256;
  f16* wpT  = wkvT + 512 * 256;

  prep_weights<<<256, 512, 0, stream>>>(Wq, Wkv, Wp, wqT, wkvT, wpT);
  for (int h = 0; h < 2; ++h) {
    xpose<<<5120, 256, 0, stream>>>(x, xf, h);
    fused_attn<<<HALF_TILES / 2, 512, 0, stream>>>(xf, bq, bkv, bp, pos,
                                                   wqT, wkvT, wpT,
                                                   (float*)d_out, h);
  }
}